// Round 10
// baseline (40.487 us; speedup 1.0000x reference)
//
#include <hip/hip_runtime.h>
#include <hip/hip_bf16.h>
#include <math.h>

#define HH 768
#define NB 8
#define LL 256
#define MM 128
#define NROW1 (NB*MM)        // 1024 dns rows
#define NROW2 (NB*LL)        // 2048 text rows
#define NROWS (NROW1+NROW2)  // 3072
#define NCB 12               // 768/64 column blocks

typedef __attribute__((ext_vector_type(8))) short  bf16x8;
typedef __attribute__((ext_vector_type(4))) float  f32x4;

static __device__ __forceinline__ unsigned int pkbf2(float a, float b) {
    __hip_bfloat162 h = __float22bfloat162_rn(make_float2(a, b));
    unsigned int u; __builtin_memcpy(&u, &h, 4); return u;
}

static __device__ __forceinline__ float fast_tanh(float x) {
    float e = __expf(2.0f * x);
    return 1.0f - 2.0f * __builtin_amdgcn_rcpf(e + 1.0f);
}

// ---------------------------------------------------------------------------
// Score GEMM v4: fp32 sources, NO prep kernel.
//  - A-fragments DIRECT from global fp32 (r9-proven row/k mapping:
//    rows wr+lc, k = k0+kk*32+lk), inline pkbf2 cvt -> bf16 frag.
//  - B staged to LDS with cvt at stage time (r3/r4-proven pattern).
//  - Loop/barrier schedule, XCD swizzle, epilogue verbatim round-7 (fastest
//    proven structure: STAGE; sync; prefetch; MFMA; sync).
// Numerics bit-identical to r7 (same RNE cvt, same MFMA order).
// ---------------------------------------------------------------------------
__global__ __launch_bounds__(256) void score_fused(
    const float* __restrict__ text, const float* __restrict__ dns,
    const float* __restrict__ Wd1, const float* __restrict__ Wt2,
    const float* __restrict__ wv1, const float* __restrict__ wv2,
    float* __restrict__ partial)
{
    __shared__ __align__(16) unsigned short Bs[64][72];

    const int t = threadIdx.x;
    const int tile = (blockIdx.x >> 3) + (blockIdx.x & 7) * 72;  // 576 = 8*72
    const int rb = tile / 12, cb = tile % 12;
    const int row0 = rb * 64, col0 = cb * 64;

    const float* Xsrc; const float* W; const float* wv; int rbase;
    if (row0 < NROW1) { Xsrc = dns;  rbase = row0;         W = Wd1; wv = wv1; }
    else              { Xsrc = text; rbase = row0 - NROW1; W = Wt2; wv = wv2; }

    // B staging mapping (verbatim r7 indices, fp32 source)
    const int sr = t >> 2;        // B row 0..63 within tile
    const int c4 = t & 3;         // 16-elem k-chunk
    const float* wp = W + (size_t)(col0 + sr) * HH + c4 * 16;

    const int l  = t & 63;
    const int w  = t >> 6;
    const int wr = w * 16;
    const int lc = l & 15;
    const int lk = (l >> 4) * 8;

    // A direct-load pointer: this lane's frag rows = rbase+wr+lc
    const float* ap = Xsrc + (size_t)(rbase + wr + lc) * HH + lk;

    f32x4 acc[4] = {};
    float4 rB[4], nB[4], rA[4], nA[4];
    // rA[0..1] = frag kk=0 (k=lk..lk+7), rA[2..3] = frag kk=1 (k=32+lk..)

    auto STAGE_B = [&]() {
        uint4 p0, p1;
        p0.x = pkbf2(rB[0].x, rB[0].y); p0.y = pkbf2(rB[0].z, rB[0].w);
        p0.z = pkbf2(rB[1].x, rB[1].y); p0.w = pkbf2(rB[1].z, rB[1].w);
        p1.x = pkbf2(rB[2].x, rB[2].y); p1.y = pkbf2(rB[2].z, rB[2].w);
        p1.z = pkbf2(rB[3].x, rB[3].y); p1.w = pkbf2(rB[3].z, rB[3].w);
        *reinterpret_cast<uint4*>(&Bs[sr][c4 * 16    ]) = p0;
        *reinterpret_cast<uint4*>(&Bs[sr][c4 * 16 + 8]) = p1;
    };
    auto LOAD_B = [&](float4 (&r)[4], int k0) {
        #pragma unroll
        for (int q = 0; q < 4; ++q) r[q] = *(const float4*)(wp + k0 + q * 4);
    };
    auto LOAD_A = [&](float4 (&r)[4], int k0) {
        r[0] = *(const float4*)(ap + k0);
        r[1] = *(const float4*)(ap + k0 + 4);
        r[2] = *(const float4*)(ap + k0 + 32);
        r[3] = *(const float4*)(ap + k0 + 36);
    };
    auto MFMA_TILE = [&]() {
        #pragma unroll
        for (int kk = 0; kk < 2; ++kk) {
            uint4 af;
            af.x = pkbf2(rA[2*kk].x,   rA[2*kk].y);
            af.y = pkbf2(rA[2*kk].z,   rA[2*kk].w);
            af.z = pkbf2(rA[2*kk+1].x, rA[2*kk+1].y);
            af.w = pkbf2(rA[2*kk+1].z, rA[2*kk+1].w);
            bf16x8 a = *reinterpret_cast<const bf16x8*>(&af);
            const int ko = kk * 32 + lk;
            #pragma unroll
            for (int n = 0; n < 4; ++n) {
                bf16x8 b = *reinterpret_cast<const bf16x8*>(&Bs[n*16 + lc][ko]);
                acc[n] = __builtin_amdgcn_mfma_f32_16x16x32_bf16(a, b, acc[n], 0, 0, 0);
            }
        }
    };

    // prologue (k0 = 0)
    LOAD_B(rB, 0);
    LOAD_A(rA, 0);

    #pragma unroll 1
    for (int k0 = 0; k0 < HH - 64; k0 += 64) {
        STAGE_B();
        __syncthreads();
        LOAD_B(nB, k0 + 64);          // prefetch next K-tile under MFMA
        LOAD_A(nA, k0 + 64);
        MFMA_TILE();
        __syncthreads();
        #pragma unroll
        for (int q = 0; q < 4; ++q) { rB[q] = nB[q]; rA[q] = nA[q]; }
    }
    STAGE_B();
    __syncthreads();
    MFMA_TILE();

    // epilogue (verbatim r7): tanh * wvec over 64 cols, 16-lane reduce
    float wvn[4];
    #pragma unroll
    for (int n = 0; n < 4; ++n) wvn[n] = wv[col0 + n*16 + lc];
    #pragma unroll
    for (int i = 0; i < 4; ++i) {
        float s = 0.f;
        #pragma unroll
        for (int n = 0; n < 4; ++n) s += fast_tanh(acc[n][i]) * wvn[n];
        s += __shfl_xor(s, 1);
        s += __shfl_xor(s, 2);
        s += __shfl_xor(s, 4);
        s += __shfl_xor(s, 8);
        if (lc == 0)
            partial[(size_t)(row0 + wr + (l >> 4)*4 + i) * NCB + cb] = s;
    }
}

// ---------------------------------------------------------------------------
// Fused tail (verbatim r7): softmax from L2-hot partials + weighted sums +
// broadcast write. Grid (8, 48), 256 threads.
// ---------------------------------------------------------------------------
__global__ __launch_bounds__(256) void tail_kernel(
    const float* __restrict__ text, const float* __restrict__ dns,
    const float* __restrict__ partial, float* __restrict__ out)
{
    const int b = blockIdx.x, hc = blockIdx.y;   // hc 0..47
    const int t = threadIdx.x;
    __shared__ float p1s[128], p2s[256], red[8];
    __shared__ __align__(16) float bt[256], bd[256];

    if (t < 128) {
        const float* pr = partial + (size_t)(b * MM + t) * NCB;
        float s = 0.f;
        #pragma unroll
        for (int c = 0; c < NCB; ++c) s += pr[c];
        p1s[t] = s;
    }
    {
        const float* pr = partial + (size_t)(NROW1 + b * LL + t) * NCB;
        float s = 0.f;
        #pragma unroll
        for (int c = 0; c < NCB; ++c) s += pr[c];
        p2s[t] = s;
    }
    __syncthreads();

    float x1 = (t < 128) ? p1s[t] : -1e30f;
    float m1 = x1;
    #pragma unroll
    for (int d = 1; d < 64; d <<= 1) m1 = fmaxf(m1, __shfl_xor(m1, d));
    if ((t & 63) == 0) red[t >> 6] = m1;
    float x2 = p2s[t];
    float m2 = x2;
    #pragma unroll
    for (int d = 1; d < 64; d <<= 1) m2 = fmaxf(m2, __shfl_xor(m2, d));
    if ((t & 63) == 0) red[4 + (t >> 6)] = m2;
    __syncthreads();
    m1 = fmaxf(fmaxf(red[0], red[1]), fmaxf(red[2], red[3]));
    m2 = fmaxf(fmaxf(red[4], red[5]), fmaxf(red[6], red[7]));

    float e1 = (t < 128) ? __expf(x1 - m1) : 0.f;
    float e2 = __expf(x2 - m2);
    __syncthreads();
    float s1 = e1, s2 = e2;
    #pragma unroll
    for (int d = 1; d < 64; d <<= 1) { s1 += __shfl_xor(s1, d); s2 += __shfl_xor(s2, d); }
    if ((t & 63) == 0) { red[t >> 6] = s1; red[4 + (t >> 6)] = s2; }
    __syncthreads();
    s1 = red[0] + red[1] + red[2] + red[3];
    s2 = red[4] + red[5] + red[6] + red[7];
    if (t < 128) p1s[t] = e1 / s1;
    p2s[t] = e2 / s2;
    __syncthreads();

    const int hh  = hc * 16 + (t & 15);
    const int rsl = t >> 4;                      // 0..15 row-slices

    const int jr0 = rsl * 16;                    // 16 text rows per slice
    float st = 0.f;
    #pragma unroll
    for (int r = 0; r < 16; ++r)
        st = fmaf(p2s[jr0 + r], text[(size_t)(b * LL + jr0 + r) * HH + hh], st);

    const int mr0 = rsl * 8;                     // 8 dns rows per slice
    float sd = 0.f;
    #pragma unroll
    for (int r = 0; r < 8; ++r)
        sd = fmaf(p1s[mr0 + r], dns[(size_t)(b * MM + mr0 + r) * HH + hh], sd);

    bt[t] = st; bd[t] = sd;
    __syncthreads();
    if (t < 128) { bt[t] += bt[t + 128]; bd[t] += bd[t + 128]; } __syncthreads();
    if (t < 64)  { bt[t] += bt[t + 64];  bd[t] += bd[t + 64];  } __syncthreads();
    if (t < 32)  { bt[t] += bt[t + 32];  bd[t] += bd[t + 32];  } __syncthreads();
    if (t < 16)  { bt[t] += bt[t + 16];  bd[t] += bd[t + 16];  }
    __syncthreads();

    const int H4 = HH / 4;                       // 192
    const int n4out = NB * LL * H4;              // 393216
    const float4* svt4 = reinterpret_cast<const float4*>(bt);
    const float4* svd4 = reinterpret_cast<const float4*>(bd);
    float4* out4 = reinterpret_cast<float4*>(out);
    #pragma unroll
    for (int i = t; i < LL * 4; i += 256) {      // 1024 = 256 rows x 4 f4
        const int ll = i >> 2, c4 = i & 3;
        const size_t o = (size_t)(b * LL + ll) * H4 + hc * 4 + c4;
        out4[o] = svt4[c4];
        out4[n4out + o] = svd4[c4];
    }
}

extern "C" void kernel_launch(void* const* d_in, const int* in_sizes, int n_in,
                              void* d_out, int out_size, void* d_ws, size_t ws_size,
                              hipStream_t stream) {
    const float* text   = (const float*)d_in[0];   // (8,256,768)
    const float* dns    = (const float*)d_in[1];   // (8,128,768)
    const float* W_d1   = (const float*)d_in[4];   // (768,768)
    const float* w_att1 = (const float*)d_in[5];   // (1536,)
    const float* W_t2   = (const float*)d_in[9];   // (768,768)
    const float* w_att2 = (const float*)d_in[10];  // (1536,)

    float* ws      = (float*)d_ws;
    float* partial = ws;                           // 36864 floats
    float* out     = (float*)d_out;

    score_fused<<<576, 256, 0, stream>>>(
        text, dns, W_d1, W_t2, w_att1 + HH, w_att2 + HH, partial);
    tail_kernel<<<dim3(NB, 48), 256, 0, stream>>>(text, dns, partial, out);
}

// Round 11
// 36.724 us; speedup vs baseline: 1.1025x; 1.1025x over previous
//
#include <hip/hip_runtime.h>
#include <hip/hip_bf16.h>
#include <math.h>

#define HH 768
#define NB 8
#define LL 256
#define MM 128
#define NROW1 (NB*MM)        // 1024 dns rows
#define NROW2 (NB*LL)        // 2048 text rows
#define NROWS (NROW1+NROW2)  // 3072
#define NCB 24               // 768/32 column blocks

typedef __attribute__((ext_vector_type(8))) short  bf16x8;
typedef __attribute__((ext_vector_type(4))) float  f32x4;

static __device__ __forceinline__ unsigned int pkbf2(float a, float b) {
    __hip_bfloat162 h = __float22bfloat162_rn(make_float2(a, b));
    unsigned int u; __builtin_memcpy(&u, &h, 4); return u;
}

static __device__ __forceinline__ float fast_tanh(float x) {
    float e = __expf(2.0f * x);
    return 1.0f - 2.0f * __builtin_amdgcn_rcpf(e + 1.0f);
}

// ---------------------------------------------------------------------------
// One-shot fp32 -> bf16 conversion of all GEMM operands. (verbatim r4-r7;
// r10 proved inline cvt on the score critical path costs ~2x score time)
// ---------------------------------------------------------------------------
__global__ __launch_bounds__(256) void prep_bf16(
    const float4* __restrict__ text, const float4* __restrict__ dns,
    const float4* __restrict__ Wd1, const float4* __restrict__ Wt2,
    uint2* __restrict__ Xb, uint2* __restrict__ Wb)
{
    const int i = blockIdx.x * 256 + threadIdx.x;   // 884736 threads exactly
    const float4* src; uint2* dst;
    if (i < 589824) {
        dst = Xb + i;
        src = (i < 196608) ? (dns + i) : (text + (i - 196608));
    } else {
        dst = Wb + (i - 589824);
        src = (i < 737280) ? (Wd1 + (i - 589824)) : (Wt2 + (i - 737280));
    }
    float4 v = *src;
    uint2 o; o.x = pkbf2(v.x, v.y); o.y = pkbf2(v.z, v.w);
    *dst = o;
}

// ---------------------------------------------------------------------------
// Score GEMM v5: column-split for occupancy. Tile 64 rows x 32 cols, grid
// 1152 = 4.5 blocks/CU = 4.5 waves/SIMD (2x r7's latency hiding -- r9/r10
// showed score is latency-bound, not DS/instruction-bound).
// A-frags direct from global bf16 (r9-proven mapping: rows wr+lc,
// k = k0+kk*32+lk, 1 uint4/frag). B (32 cols) staged to LDS, r7 schedule:
// STAGE; sync; prefetch; MFMA; sync. Full K per block -> tanh correct.
// Swizzle: 1152 = 8*144, tile = (bid>>3) + (bid&7)*144, bijective.
// ---------------------------------------------------------------------------
__global__ __launch_bounds__(256) void score_mfma(
    const unsigned short* __restrict__ Xb, const unsigned short* __restrict__ Wb,
    const float* __restrict__ wv1, const float* __restrict__ wv2,
    float* __restrict__ partial)
{
    __shared__ __align__(16) unsigned short Bs[32][72];

    const int t = threadIdx.x;
    const int tile = (blockIdx.x >> 3) + (blockIdx.x & 7) * 144;  // bijective
    const int rb = tile / NCB, cb = tile % NCB;
    const int row0 = rb * 64, col0 = cb * 32;

    const unsigned short* X = Xb + (size_t)row0 * HH;
    const unsigned short* W; const float* wv;
    if (row0 < NROW1) { W = Wb;                    wv = wv1; }
    else              { W = Wb + (size_t)HH * HH;  wv = wv2; }

    // B staging: thread t stages row sr (0..31), 8-elem k-chunk kc
    const int sr = t >> 3;
    const int kc = (t & 7) * 8;
    const unsigned short* wp = W + (size_t)(col0 + sr) * HH + kc;

    const int l  = t & 63;
    const int w  = t >> 6;
    const int wr = w * 16;
    const int lc = l & 15;
    const int lk = (l >> 4) * 8;

    // A direct-load pointer (r9-proven): lane's frag rows = row0+wr+lc
    const unsigned short* ap = X + (size_t)(wr + lc) * HH + lk;

    f32x4 acc[2] = {};
    uint4 rB, nB, rA0, rA1, nA0, nA1;

    // prologue (k0 = 0)
    rB  = *(const uint4*)(wp);
    rA0 = *(const uint4*)(ap);          // kk=0
    rA1 = *(const uint4*)(ap + 32);     // kk=1

    auto MFMA_TILE = [&]() {
        #pragma unroll
        for (int kk = 0; kk < 2; ++kk) {
            const int ko = kk * 32 + lk;
            bf16x8 a = (kk == 0) ? *(const bf16x8*)&rA0 : *(const bf16x8*)&rA1;
            #pragma unroll
            for (int n = 0; n < 2; ++n) {
                bf16x8 b = *reinterpret_cast<const bf16x8*>(&Bs[n*16 + lc][ko]);
                acc[n] = __builtin_amdgcn_mfma_f32_16x16x32_bf16(a, b, acc[n], 0, 0, 0);
            }
        }
    };

    #pragma unroll 1
    for (int k0 = 0; k0 < HH - 64; k0 += 64) {
        *reinterpret_cast<uint4*>(&Bs[sr][kc]) = rB;
        __syncthreads();
        nB  = *(const uint4*)(wp + k0 + 64);       // prefetch under MFMA
        nA0 = *(const uint4*)(ap + k0 + 64);
        nA1 = *(const uint4*)(ap + k0 + 96);
        MFMA_TILE();
        __syncthreads();
        rB = nB; rA0 = nA0; rA1 = nA1;
    }
    *reinterpret_cast<uint4*>(&Bs[sr][kc]) = rB;
    __syncthreads();
    MFMA_TILE();

    // epilogue: tanh * wvec over this block's 32 cols, 16-lane reduce
    float wvn[2];
    #pragma unroll
    for (int n = 0; n < 2; ++n) wvn[n] = wv[col0 + n*16 + lc];
    #pragma unroll
    for (int i = 0; i < 4; ++i) {
        float s = fast_tanh(acc[0][i]) * wvn[0] + fast_tanh(acc[1][i]) * wvn[1];
        s += __shfl_xor(s, 1);
        s += __shfl_xor(s, 2);
        s += __shfl_xor(s, 4);
        s += __shfl_xor(s, 8);
        if (lc == 0)
            partial[(size_t)(row0 + wr + (l >> 4)*4 + i) * NCB + cb] = s;
    }
}

// ---------------------------------------------------------------------------
// Fused tail (r7 structure; per-row reduce now over 24 partials).
// Grid (8, 48), 256 threads.
// ---------------------------------------------------------------------------
__global__ __launch_bounds__(256) void tail_kernel(
    const float* __restrict__ text, const float* __restrict__ dns,
    const float* __restrict__ partial, float* __restrict__ out)
{
    const int b = blockIdx.x, hc = blockIdx.y;   // hc 0..47
    const int t = threadIdx.x;
    __shared__ float p1s[128], p2s[256], red[8];
    __shared__ __align__(16) float bt[256], bd[256];

    if (t < 128) {
        const float* pr = partial + (size_t)(b * MM + t) * NCB;
        float s = 0.f;
        #pragma unroll
        for (int c = 0; c < NCB; ++c) s += pr[c];
        p1s[t] = s;
    }
    {
        const float* pr = partial + (size_t)(NROW1 + b * LL + t) * NCB;
        float s = 0.f;
        #pragma unroll
        for (int c = 0; c < NCB; ++c) s += pr[c];
        p2s[t] = s;
    }
    __syncthreads();

    float x1 = (t < 128) ? p1s[t] : -1e30f;
    float m1 = x1;
    #pragma unroll
    for (int d = 1; d < 64; d <<= 1) m1 = fmaxf(m1, __shfl_xor(m1, d));
    if ((t & 63) == 0) red[t >> 6] = m1;
    float x2 = p2s[t];
    float m2 = x2;
    #pragma unroll
    for (int d = 1; d < 64; d <<= 1) m2 = fmaxf(m2, __shfl_xor(m2, d));
    if ((t & 63) == 0) red[4 + (t >> 6)] = m2;
    __syncthreads();
    m1 = fmaxf(fmaxf(red[0], red[1]), fmaxf(red[2], red[3]));
    m2 = fmaxf(fmaxf(red[4], red[5]), fmaxf(red[6], red[7]));

    float e1 = (t < 128) ? __expf(x1 - m1) : 0.f;
    float e2 = __expf(x2 - m2);
    __syncthreads();
    float s1 = e1, s2 = e2;
    #pragma unroll
    for (int d = 1; d < 64; d <<= 1) { s1 += __shfl_xor(s1, d); s2 += __shfl_xor(s2, d); }
    if ((t & 63) == 0) { red[t >> 6] = s1; red[4 + (t >> 6)] = s2; }
    __syncthreads();
    s1 = red[0] + red[1] + red[2] + red[3];
    s2 = red[4] + red[5] + red[6] + red[7];
    if (t < 128) p1s[t] = e1 / s1;
    p2s[t] = e2 / s2;
    __syncthreads();

    const int hh  = hc * 16 + (t & 15);
    const int rsl = t >> 4;                      // 0..15 row-slices

    const int jr0 = rsl * 16;                    // 16 text rows per slice
    float st = 0.f;
    #pragma unroll
    for (int r = 0; r < 16; ++r)
        st = fmaf(p2s[jr0 + r], text[(size_t)(b * LL + jr0 + r) * HH + hh], st);

    const int mr0 = rsl * 8;                     // 8 dns rows per slice
    float sd = 0.f;
    #pragma unroll
    for (int r = 0; r < 8; ++r)
        sd = fmaf(p1s[mr0 + r], dns[(size_t)(b * MM + mr0 + r) * HH + hh], sd);

    bt[t] = st; bd[t] = sd;
    __syncthreads();
    if (t < 128) { bt[t] += bt[t + 128]; bd[t] += bd[t + 128]; } __syncthreads();
    if (t < 64)  { bt[t] += bt[t + 64];  bd[t] += bd[t + 64];  } __syncthreads();
    if (t < 32)  { bt[t] += bt[t + 32];  bd[t] += bd[t + 32];  } __syncthreads();
    if (t < 16)  { bt[t] += bt[t + 16];  bd[t] += bd[t + 16];  }
    __syncthreads();

    const int H4 = HH / 4;                       // 192
    const int n4out = NB * LL * H4;              // 393216
    const float4* svt4 = reinterpret_cast<const float4*>(bt);
    const float4* svd4 = reinterpret_cast<const float4*>(bd);
    float4* out4 = reinterpret_cast<float4*>(out);
    #pragma unroll
    for (int i = t; i < LL * 4; i += 256) {      // 1024 = 256 rows x 4 f4
        const int ll = i >> 2, c4 = i & 3;
        const size_t o = (size_t)(b * LL + ll) * H4 + hc * 4 + c4;
        out4[o] = svt4[c4];
        out4[n4out + o] = svd4[c4];
    }
}

extern "C" void kernel_launch(void* const* d_in, const int* in_sizes, int n_in,
                              void* d_out, int out_size, void* d_ws, size_t ws_size,
                              hipStream_t stream) {
    const float* text   = (const float*)d_in[0];   // (8,256,768)
    const float* dns    = (const float*)d_in[1];   // (8,128,768)
    const float* W_d1   = (const float*)d_in[4];   // (768,768)
    const float* w_att1 = (const float*)d_in[5];   // (1536,)
    const float* W_t2   = (const float*)d_in[9];   // (768,768)
    const float* w_att2 = (const float*)d_in[10];  // (1536,)

    float* ws      = (float*)d_ws;
    float* partial = ws;                                   // 3072*24 = 73728 f
    unsigned short* Xb = (unsigned short*)(ws + 73728);    // 2359296 bf16
    unsigned short* Wb = Xb + (size_t)NROWS * HH;          // 1179648 bf16
    float* out     = (float*)d_out;

    prep_bf16<<<3456, 256, 0, stream>>>(
        (const float4*)text, (const float4*)dns, (const float4*)W_d1,
        (const float4*)W_t2, (uint2*)Xb, (uint2*)Wb);
    score_mfma<<<1152, 256, 0, stream>>>(
        Xb, Wb, w_att1 + HH, w_att2 + HH, partial);
    tail_kernel<<<dim3(NB, 48), 256, 0, stream>>>(text, dns, partial, out);
}